// Round 5
// baseline (131.759 us; speedup 1.0000x reference)
//
#include <hip/hip_runtime.h>

#define NLAYER 255
#define SEQ    256
#define TOTJ   32640
#define CHUNKS 4
#define CHUNK_J (TOTJ / CHUNKS)   // 8160
#define CHUNK_F4 (CHUNK_J / 4)    // 2040
#define THREADS 256

typedef float  __attribute__((ext_vector_type(4))) floatx4;   // native vec for nontemporal builtin
typedef unsigned int __attribute__((ext_vector_type(4))) uintx4;

// ---------------------------------------------------------------------------
// Compile-time table: for flat element j (layer l = 1..255, pos i = 0..255-l):
//   bits [0:10)  = layer_id*4           (byte offset into w[])
//   bits [10:21) = (i + (i>>3))*4       (swizzled byte offset of c[i])
//   bits [21:32) = (hi + (hi>>3))*4     (swizzled byte offset of c[i+l])
// Swizzle s(x)=x+(x>>3): stride-4 lane access -> ~2-way bank aliasing (free).
// ---------------------------------------------------------------------------
struct TblT { unsigned int v[TOTJ]; };
static constexpr TblT make_tbl() {
    TblT t{};
    int idx = 0;
    for (int l = 1; l <= NLAYER; ++l) {
        for (int i = 0; i < 256 - l; ++i) {
            unsigned int lid4 = (unsigned int)((l - 1) * 4);
            unsigned int s0   = (unsigned int)((i + (i >> 3)) * 4);
            int hi = i + l;
            unsigned int s1   = (unsigned int)((hi + (hi >> 3)) * 4);
            t.v[idx++] = lid4 | (s0 << 10) | (s1 << 21);
        }
    }
    return t;
}
__device__ constexpr TblT TBL = make_tbl();

// ---------------------------------------------------------------------------
// Single fused kernel: grid (CHUNKS, B). Block = (chunk, row).
// Per-block partial is pre-scaled and atomically added to out[0]
// (out zeroed by a 4-byte memsetAsync before launch).
// ---------------------------------------------------------------------------
__global__ __launch_bounds__(THREADS) void main_kernel(
        const float* __restrict__ d1layer,   // B x 255
        const float* __restrict__ hvec,      // B x 32640
        const float* __restrict__ mask,      // B x 255
        float* __restrict__ out,             // scalar accumulator
        float inv_scale)                     // 1/(255*B)
{
    __shared__ float cs[288];               // swizzled cumsum
    __shared__ float w[NLAYER];             // mask^2.5 / count
    __shared__ float wsum[THREADS / 64];
    __shared__ float red[THREADS / 64];

    const int chunk = blockIdx.x;
    const int b     = blockIdx.y;
    const int t     = threadIdx.x;
    const int lane  = t & 63;
    const int wid   = t >> 6;

    // weights: layer_id = t, count = 255 - t
    if (t < NLAYER) {
        float mk = mask[b * NLAYER + t];
        w[t] = mk * mk * sqrtf(mk) / (float)(NLAYER - t);
    }

    // scan: c[t] = sum d[0..t-1], wave shuffles + cross-wave fixup
    float v = (t > 0) ? d1layer[b * NLAYER + (t - 1)] : 0.0f;
    #pragma unroll
    for (int off = 1; off < 64; off <<= 1) {
        float u = __shfl_up(v, off, 64);
        if (lane >= off) v += u;
    }
    if (lane == 63) wsum[wid] = v;
    __syncthreads();
    float woff = 0.0f;
    #pragma unroll
    for (int i = 0; i < THREADS / 64; ++i)
        if (i < wid) woff += wsum[i];
    cs[t + (t >> 3)] = v + woff;            // swizzled store
    __syncthreads();

    const floatx4* hv4 = (const floatx4*)(hvec + (size_t)b * TOTJ + chunk * CHUNK_J);
    const uintx4*  tb4 = (const uintx4*)(TBL.v + chunk * CHUNK_J);
    const char* csb = (const char*)cs;
    const char* wb  = (const char*)w;

    float acc = 0.0f;
    #pragma unroll 4
    for (int f4 = t; f4 < CHUNK_F4; f4 += THREADS) {
        floatx4 h  = __builtin_nontemporal_load(&hv4[f4]);  // streamed, no reuse
        uintx4  tv = tb4[f4];                               // L2-resident, reused

        unsigned int e0 = tv.x, e1 = tv.y, e2 = tv.z, e3 = tv.w;

        float d0 = (*(const float*)(csb + (e0 >> 21)) -
                    *(const float*)(csb + ((e0 >> 10) & 0x7FF))) - h.x;
        float d1 = (*(const float*)(csb + (e1 >> 21)) -
                    *(const float*)(csb + ((e1 >> 10) & 0x7FF))) - h.y;
        float d2 = (*(const float*)(csb + (e2 >> 21)) -
                    *(const float*)(csb + ((e2 >> 10) & 0x7FF))) - h.z;
        float d3 = (*(const float*)(csb + (e3 >> 21)) -
                    *(const float*)(csb + ((e3 >> 10) & 0x7FF))) - h.w;

        acc += d0 * d0 * *(const float*)(wb + (e0 & 0x3FF));
        acc += d1 * d1 * *(const float*)(wb + (e1 & 0x3FF));
        acc += d2 * d2 * *(const float*)(wb + (e2 & 0x3FF));
        acc += d3 * d3 * *(const float*)(wb + (e3 & 0x3FF));
    }

    // block reduction
    #pragma unroll
    for (int off = 32; off > 0; off >>= 1)
        acc += __shfl_down(acc, off, 64);
    if (lane == 0) red[wid] = acc;
    __syncthreads();
    if (t == 0) {
        float s = 0.0f;
        #pragma unroll
        for (int i = 0; i < THREADS / 64; ++i) s += red[i];
        atomicAdd(out, s * inv_scale);      // device-scope, 2048 adds total
    }
}

// ---------------------------------------------------------------------------
extern "C" void kernel_launch(void* const* d_in, const int* in_sizes, int n_in,
                              void* d_out, int out_size, void* d_ws, size_t ws_size,
                              hipStream_t stream) {
    const float* d1layer = (const float*)d_in[0];   // B x 1 x 255
    const float* hvec    = (const float*)d_in[1];   // B x 32640
    const float* mask    = (const float*)d_in[2];   // B x 255
    float* out = (float*)d_out;

    const int B = in_sizes[2] / NLAYER;             // 512
    const float inv_scale = 1.0f / ((float)NLAYER * (float)B);

    (void)hipMemsetAsync(out, 0, sizeof(float), stream);  // zero the accumulator

    dim3 grid(CHUNKS, B);
    main_kernel<<<grid, THREADS, 0, stream>>>(d1layer, hvec, mask, out, inv_scale);
}

// Round 6
// 114.833 us; speedup vs baseline: 1.1474x; 1.1474x over previous
//
#include <hip/hip_runtime.h>

#define NLAYER 255
#define SEQ    256
#define TOTJ   32640
#define CHUNKS 4
#define CHUNK_J (TOTJ / CHUNKS)   // 8160
#define CHUNK_F4 (CHUNK_J / 4)    // 2040
#define THREADS 256
#define NITER   8                 // ceil(CHUNK_F4 / THREADS); last iter guarded

typedef float        __attribute__((ext_vector_type(4))) floatx4;
typedef unsigned int __attribute__((ext_vector_type(4))) uintx4;

// ---------------------------------------------------------------------------
// Compile-time table: for flat element j (layer l = 1..255, pos i = 0..255-l):
//   bits [0:10)  = layer_id*4           (byte offset into w[])
//   bits [10:21) = (i + (i>>3))*4       (swizzled byte offset of c[i])
//   bits [21:32) = (hi + (hi>>3))*4     (swizzled byte offset of c[i+l])
// ---------------------------------------------------------------------------
struct TblT { unsigned int v[TOTJ]; };
static constexpr TblT make_tbl() {
    TblT t{};
    int idx = 0;
    for (int l = 1; l <= NLAYER; ++l) {
        for (int i = 0; i < 256 - l; ++i) {
            unsigned int lid4 = (unsigned int)((l - 1) * 4);
            unsigned int s0   = (unsigned int)((i + (i >> 3)) * 4);
            int hi = i + l;
            unsigned int s1   = (unsigned int)((hi + (hi >> 3)) * 4);
            t.v[idx++] = lid4 | (s0 << 10) | (s1 << 21);
        }
    }
    return t;
}
__device__ constexpr TblT TBL = make_tbl();

// ---------------------------------------------------------------------------
// Single fused kernel: grid (CHUNKS, B). Block = (chunk, row).
// All global loads are issued at kernel entry (d1layer/mask first, then the
// full per-thread hvec/table working set into registers); the scan runs under
// their latency, and the main loop is pure LDS+VALU with no VMEM waits.
// ---------------------------------------------------------------------------
__global__ __launch_bounds__(THREADS) void main_kernel(
        const float* __restrict__ d1layer,   // B x 255
        const float* __restrict__ hvec,      // B x 32640
        const float* __restrict__ mask,      // B x 255
        float* __restrict__ out,             // scalar accumulator
        float inv_scale)                     // 1/(255*B)
{
    __shared__ float cs[288];               // swizzled cumsum
    __shared__ float w[NLAYER];             // mask^2.5 / count
    __shared__ float wsum[THREADS / 64];
    __shared__ float red[THREADS / 64];

    const int chunk = blockIdx.x;
    const int b     = blockIdx.y;
    const int t     = threadIdx.x;
    const int lane  = t & 63;
    const int wid   = t >> 6;

    // ---- issue prologue loads FIRST (scan depends on these) ----
    float v  = (t > 0) ? d1layer[b * NLAYER + (t - 1)] : 0.0f;
    float mk = (t < NLAYER) ? mask[b * NLAYER + t] : 0.0f;

    // ---- issue the entire per-thread working set (overlaps the scan) ----
    const floatx4* hv4 = (const floatx4*)(hvec + (size_t)b * TOTJ + chunk * CHUNK_J);
    const uintx4*  tb4 = (const uintx4*)(TBL.v + chunk * CHUNK_J);

    floatx4 h[NITER];
    uintx4  tv[NITER];
    #pragma unroll
    for (int k = 0; k < NITER; ++k) {
        int f4 = t + k * THREADS;
        int idx = (k < NITER - 1 || f4 < CHUNK_F4) ? f4 : 0;  // guard only last iter
        h[k]  = hv4[idx];
        tv[k] = tb4[idx];
    }

    // ---- weights ----
    if (t < NLAYER)
        w[t] = mk * mk * sqrtf(mk) / (float)(NLAYER - t);

    // ---- scan: c[t] = sum d[0..t-1] via wave shuffles + cross-wave fixup ----
    #pragma unroll
    for (int off = 1; off < 64; off <<= 1) {
        float u = __shfl_up(v, off, 64);
        if (lane >= off) v += u;
    }
    if (lane == 63) wsum[wid] = v;
    __syncthreads();
    float woff = 0.0f;
    #pragma unroll
    for (int i = 0; i < THREADS / 64; ++i)
        if (i < wid) woff += wsum[i];
    cs[t + (t >> 3)] = v + woff;            // swizzled store
    __syncthreads();

    // ---- main loop: pure LDS + VALU ----
    const char* csb = (const char*)cs;
    const char* wb  = (const char*)w;

    float acc = 0.0f;
    #pragma unroll
    for (int k = 0; k < NITER; ++k) {
        if (k == NITER - 1 && t + k * THREADS >= CHUNK_F4) break;

        unsigned int e0 = tv[k].x, e1 = tv[k].y, e2 = tv[k].z, e3 = tv[k].w;

        float d0 = (*(const float*)(csb + (e0 >> 21)) -
                    *(const float*)(csb + ((e0 >> 10) & 0x7FF))) - h[k].x;
        float d1 = (*(const float*)(csb + (e1 >> 21)) -
                    *(const float*)(csb + ((e1 >> 10) & 0x7FF))) - h[k].y;
        float d2 = (*(const float*)(csb + (e2 >> 21)) -
                    *(const float*)(csb + ((e2 >> 10) & 0x7FF))) - h[k].z;
        float d3 = (*(const float*)(csb + (e3 >> 21)) -
                    *(const float*)(csb + ((e3 >> 10) & 0x7FF))) - h[k].w;

        acc += d0 * d0 * *(const float*)(wb + (e0 & 0x3FF));
        acc += d1 * d1 * *(const float*)(wb + (e1 & 0x3FF));
        acc += d2 * d2 * *(const float*)(wb + (e2 & 0x3FF));
        acc += d3 * d3 * *(const float*)(wb + (e3 & 0x3FF));
    }

    // ---- block reduction + atomic ----
    #pragma unroll
    for (int off = 32; off > 0; off >>= 1)
        acc += __shfl_down(acc, off, 64);
    if (lane == 0) red[wid] = acc;
    __syncthreads();
    if (t == 0) {
        float s = 0.0f;
        #pragma unroll
        for (int i = 0; i < THREADS / 64; ++i) s += red[i];
        atomicAdd(out, s * inv_scale);
    }
}

// ---------------------------------------------------------------------------
extern "C" void kernel_launch(void* const* d_in, const int* in_sizes, int n_in,
                              void* d_out, int out_size, void* d_ws, size_t ws_size,
                              hipStream_t stream) {
    const float* d1layer = (const float*)d_in[0];   // B x 1 x 255
    const float* hvec    = (const float*)d_in[1];   // B x 32640
    const float* mask    = (const float*)d_in[2];   // B x 255
    float* out = (float*)d_out;

    const int B = in_sizes[2] / NLAYER;             // 512
    const float inv_scale = 1.0f / ((float)NLAYER * (float)B);

    (void)hipMemsetAsync(out, 0, sizeof(float), stream);  // zero accumulator

    dim3 grid(CHUNKS, B);
    main_kernel<<<grid, THREADS, 0, stream>>>(d1layer, hvec, mask, out, inv_scale);
}